// Round 11
// baseline (304.383 us; speedup 1.0000x reference)
//
#include <hip/hip_runtime.h>
#include <hip/hip_fp16.h>

// DSMoE: x(8,2048,512) f32, gate_w(512,4), w1(4,512,2048), w2(4,2048,512)
// out = [ (8,2048,512) f32 ; router_sparse (16384,4) f32 ]
// R11: R9 occupancy (CB=260: gemm2 grid 1040 fills 1024-resident; R10's
//      CB=130 left half the GPU idle in gemm2) + R10 conflict-free swizzle
//      + 5 blocks/CU (LDS exactly 32KB both gemms: slist dropped from gemm1,
//      launch_bounds(256,5); 5x32KB = 160KB exact).

#define NTOK  16384
#define CDIM  512
#define FF    2048
#define NEXP  4
#define CAP   33280    // 32768 + 4*128 padding headroom (260 blocks of 128)
#define NBLK  260
#define BM    128
#define BN1   128      // gemm1 N-tile (ff cols)
#define BN2   128      // gemm2 N-tile (out cols)
#define BK    32
#define CPAD  32       // ints per counter line (128B)

typedef _Float16 f16;
typedef __attribute__((ext_vector_type(8))) _Float16 f16x8;
typedef __attribute__((ext_vector_type(4))) _Float16 f16x4;
typedef __attribute__((ext_vector_type(4))) float f32x4;

__device__ __forceinline__ void gload16(const void* g, void* l) {
  __builtin_amdgcn_global_load_lds(
      (const __attribute__((address_space(1))) unsigned int*)g,
      (__attribute__((address_space(3))) unsigned int*)l, 16, 0, 0);
}

// gelu(v) = 0.5 v (1 + erf(v/sqrt2)), erf via Abramowitz-Stegun 7.1.26
__device__ __forceinline__ float gelu_fast(float v) {
  float az = fabsf(v) * 0.7071067811865476f;
  float t = __builtin_amdgcn_rcpf(fmaf(0.3275911f, az, 1.0f));
  float p = fmaf(fmaf(fmaf(fmaf(1.061405429f, t, -1.453152027f), t,
                           1.421413741f), t, -0.284496736f), t, 0.254829592f) * t;
  float e = __builtin_amdgcn_exp2f(az * az * -1.4426950408889634f);
  float erfa = fmaf(-p, e, 1.0f);
  float u = copysignf(erfa, v);
  return 0.5f * v * (1.0f + u);
}

// bijective XCD swizzle for any nwg (m204 form)
__device__ __forceinline__ int xcd_swz(int bid, int nwg) {
  int q = nwg >> 3, r = nwg & 7;
  int x = bid & 7, o = bid >> 3;
  return (x < r ? x * (q + 1) : r * (q + 1) + (x - r) * q) + o;
}

// ---------------- small utility kernels ----------------

__global__ __launch_bounds__(256) void k_init(int* list, int* cnt) {
  int i = blockIdx.x * 256 + threadIdx.x;
  if (i < CAP) list[i] = -1;
  if (i < 4) cnt[i * CPAD] = 0;
}

// transpose-cast: in [E][R][Cc] f32 -> out [E][Cc][R] f16, 64x64 tiles
__global__ __launch_bounds__(256) void k_cast_t(const float* __restrict__ in,
                                                f16* __restrict__ out, int R, int Cc) {
  __shared__ f16 T[64][72];
  int ez = blockIdx.z;
  const float* ine = in + (size_t)ez * R * Cc;
  f16* oute = out + (size_t)ez * R * Cc;
  int c0 = blockIdx.x * 64;
  int r0 = blockIdx.y * 64;
  int t = threadIdx.x;
  {
    int rr = t >> 2, cc = (t & 3) * 16;
    const float* src = ine + (size_t)(r0 + rr) * Cc + c0 + cc;
    union { f16 h[16]; uint4 u[2]; } pk;
#pragma unroll
    for (int j = 0; j < 16; j += 4) {
      float4 a = *(const float4*)(src + j);
      pk.h[j] = (f16)a.x; pk.h[j + 1] = (f16)a.y;
      pk.h[j + 2] = (f16)a.z; pk.h[j + 3] = (f16)a.w;
    }
    *(uint4*)&T[rr][cc] = pk.u[0];
    *(uint4*)&T[rr][cc + 8] = pk.u[1];
  }
  __syncthreads();
  {
    int oc = t >> 2, orr = (t & 3) * 16;
    union { f16 h[16]; uint4 u[2]; } pk;
#pragma unroll
    for (int j = 0; j < 16; ++j) pk.h[j] = T[orr + j][oc];
    f16* dst = oute + (size_t)(c0 + oc) * R + r0 + orr;
    *(uint4*)dst = pk.u[0];
    *(uint4*)(dst + 8) = pk.u[1];
  }
}

// ---------------- router (fp32 exact) + fused x->fp16 cast ----------------

__global__ __launch_bounds__(256) void k_router(const float* __restrict__ x,
                                                const float* __restrict__ gw,
                                                f16* __restrict__ xh,
                                                float* __restrict__ rout,
                                                float4* __restrict__ tokinfo,
                                                int* __restrict__ cnt) {
  __shared__ int lcnt[4];
  int tid = threadIdx.x;
  if (tid < 4) lcnt[tid] = 0;
  __syncthreads();
  int wv = tid >> 6, lane = tid & 63;
  const float4* g = ((const float4*)gw) + lane * 8;
  float4 gv[8];
#pragma unroll
  for (int j = 0; j < 8; ++j) gv[j] = g[j];

  int tok0 = blockIdx.x * 64 + wv * 16;
  for (int i = 0; i < 16; ++i) {
    int tok = tok0 + i;
    const float4* xr = (const float4*)(x + (size_t)tok * CDIM + lane * 8);
    float4 a0 = xr[0], a1 = xr[1];
    union { f16 h[8]; uint4 u; } pk;
    pk.h[0] = (f16)a0.x; pk.h[1] = (f16)a0.y; pk.h[2] = (f16)a0.z; pk.h[3] = (f16)a0.w;
    pk.h[4] = (f16)a1.x; pk.h[5] = (f16)a1.y; pk.h[6] = (f16)a1.z; pk.h[7] = (f16)a1.w;
    *(uint4*)(xh + (size_t)tok * CDIM + lane * 8) = pk.u;
    float xv[8] = {a0.x, a0.y, a0.z, a0.w, a1.x, a1.y, a1.z, a1.w};
    float l0 = 0, l1 = 0, l2 = 0, l3 = 0;
#pragma unroll
    for (int j = 0; j < 8; ++j) {
      float4 g4 = gv[j];
      l0 = fmaf(xv[j], g4.x, l0); l1 = fmaf(xv[j], g4.y, l1);
      l2 = fmaf(xv[j], g4.z, l2); l3 = fmaf(xv[j], g4.w, l3);
    }
#pragma unroll
    for (int off = 32; off; off >>= 1) {
      l0 += __shfl_xor(l0, off); l1 += __shfl_xor(l1, off);
      l2 += __shfl_xor(l2, off); l3 += __shfl_xor(l3, off);
    }
    if (lane == 0) {
      float lg[4] = {l0, l1, l2, l3};
      float m = fmaxf(fmaxf(lg[0], lg[1]), fmaxf(lg[2], lg[3]));
      float p[4], s = 0.f;
#pragma unroll
      for (int e = 0; e < 4; ++e) { p[e] = expf(lg[e] - m); s += p[e]; }
      int i0 = 0;
#pragma unroll
      for (int e = 1; e < 4; ++e) if (lg[e] > lg[i0]) i0 = e;
      int i1 = -1;
#pragma unroll
      for (int e = 0; e < 4; ++e)
        if (e != i0 && (i1 < 0 || lg[e] > lg[i1])) i1 = e;
      float p0 = p[i0] / s, p1 = p[i1] / s;
      float ss = fmaxf(p0 + p1, 1e-6f);
      float w0 = p0 / ss, w1v = p1 / ss;
      float r[4] = {0.f, 0.f, 0.f, 0.f};
      r[i0] = w0; r[i1] = w1v;
      *(float4*)(rout + tok * 4) = make_float4(r[0], r[1], r[2], r[3]);
      float4 ti;
      ti.x = __int_as_float(i0); ti.y = __int_as_float(i1); ti.z = w0; ti.w = w1v;
      tokinfo[tok] = ti;
      atomicAdd(&lcnt[i0], 1);
      atomicAdd(&lcnt[i1], 1);
    }
  }
  __syncthreads();
  if (tid < 4) atomicAdd(cnt + tid * CPAD, lcnt[tid]);
}

__global__ void k_bases(const int* __restrict__ cnt, int* __restrict__ base,
                        int* __restrict__ cursor) {
  if (threadIdx.x == 0 && blockIdx.x == 0) {
    int b = 0;
#pragma unroll
    for (int e = 0; e < 4; ++e) {
      base[e] = b; cursor[e * CPAD] = b;
      b += (cnt[e * CPAD] + 127) & ~127;   // 128-aligned regions
    }
    base[4] = b;
  }
}

// slot assignment + inverse map (token -> its 2 slots)
__global__ __launch_bounds__(256) void k_assign(const float4* __restrict__ tokinfo,
                                                int* cursor, int* __restrict__ list,
                                                int2* __restrict__ tokslot) {
  __shared__ int lcnt[4], lbase[4];
  int tid = threadIdx.x;
  if (tid < 4) lcnt[tid] = 0;
  __syncthreads();
  int t0 = blockIdx.x * 1024 + tid * 4;
  float4 ti[4]; int lo0[4], lo1[4];
#pragma unroll
  for (int j = 0; j < 4; ++j) {
    ti[j] = tokinfo[t0 + j];
    lo0[j] = atomicAdd(&lcnt[__float_as_int(ti[j].x)], 1);
    lo1[j] = atomicAdd(&lcnt[__float_as_int(ti[j].y)], 1);
  }
  __syncthreads();
  if (tid < 4) lbase[tid] = atomicAdd(cursor + tid * CPAD, lcnt[tid]);
  __syncthreads();
#pragma unroll
  for (int j = 0; j < 4; ++j) {
    int s0 = lbase[__float_as_int(ti[j].x)] + lo0[j];
    list[s0] = t0 + j;
    int s1 = lbase[__float_as_int(ti[j].y)] + lo1[j];
    list[s1] = t0 + j;
    tokslot[t0 + j] = make_int2(s0, s1);
  }
}

// ---------------- pass 1: H[slot, :] = gelu(x[list] @ W1e) ----------------
// 128x128 tile, BK=32, dbuf 2x16KB = exactly 32KB LDS, 5 blocks/CU.

__global__ __launch_bounds__(256, 5) void k_gemm1(const f16* __restrict__ xh,
                                                  const f16* __restrict__ w1t, // [E][FF][C]
                                                  const int* __restrict__ list,
                                                  const int* __restrict__ base,
                                                  f16* __restrict__ H, int cb, int nwg) {
  __shared__ __align__(16) char smem[32768];
  int tid = threadIdx.x;
  int wk = xcd_swz(blockIdx.x, nwg);
  int bx = wk >> 4, by = wk & 15;
  int m0 = (cb + bx) * BM;
  int mloc = bx * BM;
  int h0 = by * BN1;
  int e = 0;
#pragma unroll
  for (int i = 1; i < 4; ++i) if (m0 >= base[i]) e = i;

  int tokr[2];
#pragma unroll
  for (int i = 0; i < 2; ++i) {          // 4 threads share each entry (L2-served)
    int v = list[m0 + i * 64 + (tid >> 2)];
    tokr[i] = v < 0 ? 0 : v;             // pads -> token 0: garbage, never read back
  }

  const f16* wB = w1t + (size_t)(e * FF + h0) * CDIM;
  // byte-in-row (64B rows); involution covers all 8 bank groups per 8 rows
  int kbs = ((tid & 3) * 16) ^ (((tid >> 3) & 3) << 4);

  f32x4 acc[4][4] = {};
  int lane = tid & 63, w = tid >> 6, wr = w >> 1, wc = w & 1;

  auto stage = [&](int kk, int p) {   // 4 gloads: A 128x32, B 128x32
    char* s = smem + p * 16384;
#pragma unroll
    for (int i = 0; i < 2; ++i) {   // A: gathered x rows
      gload16(xh + (size_t)tokr[i] * CDIM + kk * BK + (kbs >> 1),
              s + i * 4096 + tid * 16);
    }
#pragma unroll
    for (int i = 0; i < 2; ++i) {   // B: w1t rows (ff cols)
      int row = i * 64 + (tid >> 2);
      gload16(wB + (size_t)row * CDIM + kk * BK + (kbs >> 1),
              s + 8192 + i * 4096 + tid * 16);
    }
  };

  auto compute = [&](int p) {
    const char* s = smem + p * 16384;
    f16x8 af[4], bfr[4];
    int kb = (lane >> 4) * 16;
#pragma unroll
    for (int fr = 0; fr < 4; ++fr) {
      int row = wr * 64 + fr * 16 + (lane & 15);
      af[fr] = *(const f16x8*)(s + row * 64 + (kb ^ (((row >> 1) & 3) << 4)));
    }
#pragma unroll
    for (int fc = 0; fc < 4; ++fc) {
      int col = wc * 64 + fc * 16 + (lane & 15);
      bfr[fc] = *(const f16x8*)(s + 8192 + col * 64 + (kb ^ (((col >> 1) & 3) << 4)));
    }
#pragma unroll
    for (int fr = 0; fr < 4; ++fr)
#pragma unroll
      for (int fc = 0; fc < 4; ++fc)
        acc[fr][fc] = __builtin_amdgcn_mfma_f32_16x16x32_f16(af[fr], bfr[fc],
                                                             acc[fr][fc], 0, 0, 0);
  };

  stage(0, 0);
  __syncthreads();
  for (int kk = 0; kk < 16; ++kk) {      // K = 512, BK = 32
    if (kk < 15) stage(kk + 1, (kk + 1) & 1);
    __builtin_amdgcn_sched_barrier(0);
    __builtin_amdgcn_s_setprio(1);
    compute(kk & 1);
    __builtin_amdgcn_s_setprio(0);
    __syncthreads();
  }

  // epilogue: gelu -> fp16, LDS repack [128][256B], coalesced 16B stores
#pragma unroll
  for (int fr = 0; fr < 4; ++fr)
#pragma unroll
    for (int fc = 0; fc < 4; ++fc)
#pragma unroll
      for (int i = 0; i < 4; ++i) {
        int row = wr * 64 + fr * 16 + (lane >> 4) * 4 + i;
        int col = wc * 64 + fc * 16 + (lane & 15);
        float v = gelu_fast(acc[fr][fc][i]);
        int off = (row * 256 + col * 2) ^ ((row & 7) << 4);
        *(f16*)(smem + off) = (f16)v;
      }
  __syncthreads();
#pragma unroll
  for (int j = 0; j < 8; ++j) {
    int row = j * 16 + (tid >> 4);
    int colb = ((tid & 15) * 16) ^ ((row & 7) << 4);
    uint4 v = *(const uint4*)(smem + row * 256 + colb);
    *(uint4*)((char*)H + ((size_t)(mloc + row) * FF + h0) * 2 + (tid & 15) * 16) = v;
  }
}

// ---------------- pass 2: Y[slot] = H[slot] @ W2e  (K = FF = 2048) ----------------
// 128x128 tile, BK=32, dbuf 2x16KB = exactly 32KB LDS, 5 blocks/CU. Grid CB*4.

__global__ __launch_bounds__(256, 5) void k_gemm2(const f16* __restrict__ H,
                                                  const f16* __restrict__ w2t, // [E][C][FF]
                                                  const int* __restrict__ base,
                                                  f16* __restrict__ Y, int cb, int nwg) {
  __shared__ __align__(16) char smem[32768];
  int tid = threadIdx.x;
  int wk = xcd_swz(blockIdx.x, nwg);
  int bx = wk >> 2, by = wk & 3;      // 512/128 = 4 out panels, fastest
  int m0 = (cb + bx) * BM;
  int mloc = bx * BM;
  int c0 = by * BN2;
  int e = 0;
#pragma unroll
  for (int i = 1; i < 4; ++i) if (m0 >= base[i]) e = i;

  const f16* pA = H + (size_t)mloc * FF;
  const f16* wB = w2t + (size_t)(e * CDIM + c0) * FF;
  int kbs = ((tid & 3) * 16) ^ (((tid >> 3) & 3) << 4);

  f32x4 acc[4][4] = {};
  int lane = tid & 63, w = tid >> 6, wr = w >> 1, wc = w & 1;

  auto stage = [&](int kk, int p) {   // 4 gloads: A 128x32, B 128x32
    char* s = smem + p * 16384;
#pragma unroll
    for (int i = 0; i < 2; ++i) {   // A: H rows (local slots)
      int row = i * 64 + (tid >> 2);
      gload16(pA + (size_t)row * FF + kk * BK + (kbs >> 1),
              s + i * 4096 + tid * 16);
    }
#pragma unroll
    for (int i = 0; i < 2; ++i) {   // B: w2t rows (out cols)
      int row = i * 64 + (tid >> 2);
      gload16(wB + (size_t)row * FF + kk * BK + (kbs >> 1),
              s + 8192 + i * 4096 + tid * 16);
    }
  };

  auto compute = [&](int p) {
    const char* s = smem + p * 16384;
    f16x8 af[4], bfr[4];
    int kb = (lane >> 4) * 16;
#pragma unroll
    for (int fr = 0; fr < 4; ++fr) {
      int row = wr * 64 + fr * 16 + (lane & 15);
      af[fr] = *(const f16x8*)(s + row * 64 + (kb ^ (((row >> 1) & 3) << 4)));
    }
#pragma unroll
    for (int fc = 0; fc < 4; ++fc) {
      int col = wc * 64 + fc * 16 + (lane & 15);
      bfr[fc] = *(const f16x8*)(s + 8192 + col * 64 + (kb ^ (((col >> 1) & 3) << 4)));
    }
#pragma unroll
    for (int fr = 0; fr < 4; ++fr)
#pragma unroll
      for (int fc = 0; fc < 4; ++fc)
        acc[fr][fc] = __builtin_amdgcn_mfma_f32_16x16x32_f16(af[fr], bfr[fc],
                                                             acc[fr][fc], 0, 0, 0);
  };

  stage(0, 0);
  __syncthreads();
  for (int kk = 0; kk < 64; ++kk) {      // K = 2048, BK = 32
    if (kk < 63) stage(kk + 1, (kk + 1) & 1);
    __builtin_amdgcn_sched_barrier(0);
    __builtin_amdgcn_s_setprio(1);
    compute(kk & 1);
    __builtin_amdgcn_s_setprio(0);
    __syncthreads();
  }

  // epilogue: f16 -> LDS repack [128][256B] -> coalesced 16B stores
#pragma unroll
  for (int fr = 0; fr < 4; ++fr)
#pragma unroll
    for (int fc = 0; fc < 4; ++fc)
#pragma unroll
      for (int i = 0; i < 4; ++i) {
        int row = wr * 64 + fr * 16 + (lane >> 4) * 4 + i;
        int col = wc * 64 + fc * 16 + (lane & 15);
        int off = (row * 256 + col * 2) ^ ((row & 7) << 4);
        *(f16*)(smem + off) = (f16)acc[fr][fc][i];
      }
  __syncthreads();
#pragma unroll
  for (int j = 0; j < 8; ++j) {
    int row = j * 16 + (tid >> 4);
    int colb = ((tid & 15) * 16) ^ ((row & 7) << 4);
    uint4 v = *(const uint4*)(smem + row * 256 + colb);
    *(uint4*)((char*)Y + ((size_t)(m0 + row) * CDIM + c0) * 2 + (tid & 15) * 16) = v;
  }
}

// ---------------- combine: out[tok] = w0*Y[s0] + w1*Y[s1] ----------------

__global__ __launch_bounds__(256) void k_combine(const f16* __restrict__ Y,
                                                 const float4* __restrict__ tokinfo,
                                                 const int2* __restrict__ tokslot,
                                                 float* __restrict__ out) {
  int gid = blockIdx.x * 256 + threadIdx.x;
  int tok = gid >> 7;
  int cc = (gid & 127) * 4;
  int2 sl = tokslot[tok];
  float4 ti = tokinfo[tok];
  f16x4 y0 = *(const f16x4*)(Y + (size_t)sl.x * CDIM + cc);
  f16x4 y1 = *(const f16x4*)(Y + (size_t)sl.y * CDIM + cc);
  float w0 = ti.z, w1 = ti.w;
  float4 o;
  o.x = w0 * (float)y0[0] + w1 * (float)y1[0];
  o.y = w0 * (float)y0[1] + w1 * (float)y1[1];
  o.z = w0 * (float)y0[2] + w1 * (float)y1[2];
  o.w = w0 * (float)y0[3] + w1 * (float)y1[3];
  *(float4*)(out + (size_t)tok * CDIM + cc) = o;
}

// ---------------- host ----------------

extern "C" void kernel_launch(void* const* d_in, const int* in_sizes, int n_in,
                              void* d_out, int out_size, void* d_ws, size_t ws_size,
                              hipStream_t stream) {
  const float* x  = (const float*)d_in[0];
  const float* gw = (const float*)d_in[1];
  const float* w1 = (const float*)d_in[2];
  const float* w2 = (const float*)d_in[3];
  float* out  = (float*)d_out;
  float* rout = out + (size_t)NTOK * CDIM;

  char* ws = (char*)d_ws;
  f16* xh      = (f16*)ws;      ws += (size_t)NTOK * CDIM * 2;       // 16.78 MB
  f16* w1t     = (f16*)ws;      ws += (size_t)NEXP * FF * CDIM * 2;  //  8.39 MB
  f16* w2t     = (f16*)ws;      ws += (size_t)NEXP * FF * CDIM * 2;  //  8.39 MB
  f16* Ybuf    = (f16*)ws;      ws += (size_t)CAP * CDIM * 2;        // 34.08 MB
  float4* tokinfo = (float4*)ws; ws += (size_t)NTOK * 16;            //  0.26 MB
  int2* tokslot = (int2*)ws;    ws += (size_t)NTOK * 8;              //  0.13 MB
  int* list    = (int*)ws;      ws += (size_t)CAP * 4;               //  0.13 MB
  int* cnt     = (int*)ws;      ws += 4 * CPAD * 4;
  int* base    = (int*)ws;      ws += 64;
  int* cursor  = (int*)ws;      ws += 4 * CPAD * 4;
  f16* Hbuf    = (f16*)ws;      // CB*128*FF f16, sized by ladder below

  size_t base_bytes = (size_t)(ws - (char*)d_ws);
  const int opts[12] = {260, 130, 65, 52, 26, 20, 13, 10, 5, 4, 2, 1};
  int CB = 1;
  for (int oi = 0; oi < 12; ++oi) {
    if (base_bytes + (size_t)opts[oi] * BM * FF * 2 <= ws_size) { CB = opts[oi]; break; }
  }

  k_init<<<(CAP + 255) / 256, 256, 0, stream>>>(list, cnt);
  k_cast_t<<<dim3(FF / 64, CDIM / 64, NEXP), 256, 0, stream>>>(w1, w1t, CDIM, FF);
  k_cast_t<<<dim3(CDIM / 64, FF / 64, NEXP), 256, 0, stream>>>(w2, w2t, FF, CDIM);
  k_router<<<NTOK / 64, 256, 0, stream>>>(x, gw, xh, rout, tokinfo, cnt);
  k_bases<<<1, 64, 0, stream>>>(cnt, base, cursor);
  k_assign<<<NTOK / 1024, 256, 0, stream>>>(tokinfo, cursor, list, tokslot);

  for (int cb = 0; cb < NBLK; cb += CB) {
    int n1 = CB * 16, n2 = CB * 4;
    k_gemm1<<<n1, 256, 0, stream>>>(xh, w1t, list, base, Hbuf, cb, n1);
    k_gemm2<<<n2, 256, 0, stream>>>(Hbuf, w2t, base, Ybuf, cb, n2);
  }
  k_combine<<<NTOK * CDIM / 4 / 256, 256, 0, stream>>>(Ybuf, tokinfo, tokslot, out);
}

// Round 12
// 264.532 us; speedup vs baseline: 1.1506x; 1.1506x over previous
//
#include <hip/hip_runtime.h>
#include <hip/hip_fp16.h>

// DSMoE: x(8,2048,512) f32, gate_w(512,4), w1(4,512,2048), w2(4,2048,512)
// out = [ (8,2048,512) f32 ; router_sparse (16384,4) f32 ]
// R12: R9-exact (best, 268us: CB=260, 4 blk/CU, slist) + ONLY the swizzle
//      involution fix from R10 (conflicts 8.5M -> 0). R11 lesson: 5 blk/CU
//      blew L2/L3 (FETCH 36->125MB) and no-slist/VGPR-48 hurt ILP.

#define NTOK  16384
#define CDIM  512
#define FF    2048
#define NEXP  4
#define CAP   33280    // 32768 + 4*128 padding headroom (260 blocks of 128)
#define NBLK  260
#define BM    128
#define BN1   128      // gemm1 N-tile (ff cols)
#define BN2   128      // gemm2 N-tile (out cols)
#define BK    32
#define CPAD  32       // ints per counter line (128B)

typedef _Float16 f16;
typedef __attribute__((ext_vector_type(8))) _Float16 f16x8;
typedef __attribute__((ext_vector_type(4))) _Float16 f16x4;
typedef __attribute__((ext_vector_type(4))) float f32x4;

__device__ __forceinline__ void gload16(const void* g, void* l) {
  __builtin_amdgcn_global_load_lds(
      (const __attribute__((address_space(1))) unsigned int*)g,
      (__attribute__((address_space(3))) unsigned int*)l, 16, 0, 0);
}

// gelu(v) = 0.5 v (1 + erf(v/sqrt2)), erf via Abramowitz-Stegun 7.1.26
__device__ __forceinline__ float gelu_fast(float v) {
  float az = fabsf(v) * 0.7071067811865476f;
  float t = __builtin_amdgcn_rcpf(fmaf(0.3275911f, az, 1.0f));
  float p = fmaf(fmaf(fmaf(fmaf(1.061405429f, t, -1.453152027f), t,
                           1.421413741f), t, -0.284496736f), t, 0.254829592f) * t;
  float e = __builtin_amdgcn_exp2f(az * az * -1.4426950408889634f);
  float erfa = fmaf(-p, e, 1.0f);
  float u = copysignf(erfa, v);
  return 0.5f * v * (1.0f + u);
}

// bijective XCD swizzle for any nwg (m204 form)
__device__ __forceinline__ int xcd_swz(int bid, int nwg) {
  int q = nwg >> 3, r = nwg & 7;
  int x = bid & 7, o = bid >> 3;
  return (x < r ? x * (q + 1) : r * (q + 1) + (x - r) * q) + o;
}

// ---------------- small utility kernels ----------------

__global__ __launch_bounds__(256) void k_init(int* list, int* cnt) {
  int i = blockIdx.x * 256 + threadIdx.x;
  if (i < CAP) list[i] = -1;
  if (i < 4) cnt[i * CPAD] = 0;
}

// transpose-cast: in [E][R][Cc] f32 -> out [E][Cc][R] f16, 64x64 tiles
__global__ __launch_bounds__(256) void k_cast_t(const float* __restrict__ in,
                                                f16* __restrict__ out, int R, int Cc) {
  __shared__ f16 T[64][72];
  int ez = blockIdx.z;
  const float* ine = in + (size_t)ez * R * Cc;
  f16* oute = out + (size_t)ez * R * Cc;
  int c0 = blockIdx.x * 64;
  int r0 = blockIdx.y * 64;
  int t = threadIdx.x;
  {
    int rr = t >> 2, cc = (t & 3) * 16;
    const float* src = ine + (size_t)(r0 + rr) * Cc + c0 + cc;
    union { f16 h[16]; uint4 u[2]; } pk;
#pragma unroll
    for (int j = 0; j < 16; j += 4) {
      float4 a = *(const float4*)(src + j);
      pk.h[j] = (f16)a.x; pk.h[j + 1] = (f16)a.y;
      pk.h[j + 2] = (f16)a.z; pk.h[j + 3] = (f16)a.w;
    }
    *(uint4*)&T[rr][cc] = pk.u[0];
    *(uint4*)&T[rr][cc + 8] = pk.u[1];
  }
  __syncthreads();
  {
    int oc = t >> 2, orr = (t & 3) * 16;
    union { f16 h[16]; uint4 u[2]; } pk;
#pragma unroll
    for (int j = 0; j < 16; ++j) pk.h[j] = T[orr + j][oc];
    f16* dst = oute + (size_t)(c0 + oc) * R + r0 + orr;
    *(uint4*)dst = pk.u[0];
    *(uint4*)(dst + 8) = pk.u[1];
  }
}

// ---------------- router (fp32 exact) + fused x->fp16 cast ----------------

__global__ __launch_bounds__(256) void k_router(const float* __restrict__ x,
                                                const float* __restrict__ gw,
                                                f16* __restrict__ xh,
                                                float* __restrict__ rout,
                                                float4* __restrict__ tokinfo,
                                                int* __restrict__ cnt) {
  __shared__ int lcnt[4];
  int tid = threadIdx.x;
  if (tid < 4) lcnt[tid] = 0;
  __syncthreads();
  int wv = tid >> 6, lane = tid & 63;
  const float4* g = ((const float4*)gw) + lane * 8;
  float4 gv[8];
#pragma unroll
  for (int j = 0; j < 8; ++j) gv[j] = g[j];

  int tok0 = blockIdx.x * 64 + wv * 16;
  for (int i = 0; i < 16; ++i) {
    int tok = tok0 + i;
    const float4* xr = (const float4*)(x + (size_t)tok * CDIM + lane * 8);
    float4 a0 = xr[0], a1 = xr[1];
    union { f16 h[8]; uint4 u; } pk;
    pk.h[0] = (f16)a0.x; pk.h[1] = (f16)a0.y; pk.h[2] = (f16)a0.z; pk.h[3] = (f16)a0.w;
    pk.h[4] = (f16)a1.x; pk.h[5] = (f16)a1.y; pk.h[6] = (f16)a1.z; pk.h[7] = (f16)a1.w;
    *(uint4*)(xh + (size_t)tok * CDIM + lane * 8) = pk.u;
    float xv[8] = {a0.x, a0.y, a0.z, a0.w, a1.x, a1.y, a1.z, a1.w};
    float l0 = 0, l1 = 0, l2 = 0, l3 = 0;
#pragma unroll
    for (int j = 0; j < 8; ++j) {
      float4 g4 = gv[j];
      l0 = fmaf(xv[j], g4.x, l0); l1 = fmaf(xv[j], g4.y, l1);
      l2 = fmaf(xv[j], g4.z, l2); l3 = fmaf(xv[j], g4.w, l3);
    }
#pragma unroll
    for (int off = 32; off; off >>= 1) {
      l0 += __shfl_xor(l0, off); l1 += __shfl_xor(l1, off);
      l2 += __shfl_xor(l2, off); l3 += __shfl_xor(l3, off);
    }
    if (lane == 0) {
      float lg[4] = {l0, l1, l2, l3};
      float m = fmaxf(fmaxf(lg[0], lg[1]), fmaxf(lg[2], lg[3]));
      float p[4], s = 0.f;
#pragma unroll
      for (int e = 0; e < 4; ++e) { p[e] = expf(lg[e] - m); s += p[e]; }
      int i0 = 0;
#pragma unroll
      for (int e = 1; e < 4; ++e) if (lg[e] > lg[i0]) i0 = e;
      int i1 = -1;
#pragma unroll
      for (int e = 0; e < 4; ++e)
        if (e != i0 && (i1 < 0 || lg[e] > lg[i1])) i1 = e;
      float p0 = p[i0] / s, p1 = p[i1] / s;
      float ss = fmaxf(p0 + p1, 1e-6f);
      float w0 = p0 / ss, w1v = p1 / ss;
      float r[4] = {0.f, 0.f, 0.f, 0.f};
      r[i0] = w0; r[i1] = w1v;
      *(float4*)(rout + tok * 4) = make_float4(r[0], r[1], r[2], r[3]);
      float4 ti;
      ti.x = __int_as_float(i0); ti.y = __int_as_float(i1); ti.z = w0; ti.w = w1v;
      tokinfo[tok] = ti;
      atomicAdd(&lcnt[i0], 1);
      atomicAdd(&lcnt[i1], 1);
    }
  }
  __syncthreads();
  if (tid < 4) atomicAdd(cnt + tid * CPAD, lcnt[tid]);
}

__global__ void k_bases(const int* __restrict__ cnt, int* __restrict__ base,
                        int* __restrict__ cursor) {
  if (threadIdx.x == 0 && blockIdx.x == 0) {
    int b = 0;
#pragma unroll
    for (int e = 0; e < 4; ++e) {
      base[e] = b; cursor[e * CPAD] = b;
      b += (cnt[e * CPAD] + 127) & ~127;   // 128-aligned regions
    }
    base[4] = b;
  }
}

// slot assignment + inverse map (token -> its 2 slots)
__global__ __launch_bounds__(256) void k_assign(const float4* __restrict__ tokinfo,
                                                int* cursor, int* __restrict__ list,
                                                int2* __restrict__ tokslot) {
  __shared__ int lcnt[4], lbase[4];
  int tid = threadIdx.x;
  if (tid < 4) lcnt[tid] = 0;
  __syncthreads();
  int t0 = blockIdx.x * 1024 + tid * 4;
  float4 ti[4]; int lo0[4], lo1[4];
#pragma unroll
  for (int j = 0; j < 4; ++j) {
    ti[j] = tokinfo[t0 + j];
    lo0[j] = atomicAdd(&lcnt[__float_as_int(ti[j].x)], 1);
    lo1[j] = atomicAdd(&lcnt[__float_as_int(ti[j].y)], 1);
  }
  __syncthreads();
  if (tid < 4) lbase[tid] = atomicAdd(cursor + tid * CPAD, lcnt[tid]);
  __syncthreads();
#pragma unroll
  for (int j = 0; j < 4; ++j) {
    int s0 = lbase[__float_as_int(ti[j].x)] + lo0[j];
    list[s0] = t0 + j;
    int s1 = lbase[__float_as_int(ti[j].y)] + lo1[j];
    list[s1] = t0 + j;
    tokslot[t0 + j] = make_int2(s0, s1);
  }
}

// ---------------- pass 1: H[slot, :] = gelu(x[list] @ W1e) ----------------
// 128x128 tile, BK=32, dbuf 2x16KB, 4 blocks/CU, stage-early + syncthreads.

__global__ __launch_bounds__(256, 4) void k_gemm1(const f16* __restrict__ xh,
                                                  const f16* __restrict__ w1t, // [E][FF][C]
                                                  const int* __restrict__ list,
                                                  const int* __restrict__ base,
                                                  f16* __restrict__ H, int cb, int nwg) {
  __shared__ __align__(16) char smem[32768 + 512];
  int* slist = (int*)(smem + 32768);
  int tid = threadIdx.x;
  int wk = xcd_swz(blockIdx.x, nwg);
  int bx = wk >> 4, by = wk & 15;
  int m0 = (cb + bx) * BM;
  int mloc = bx * BM;
  int h0 = by * BN1;
  int e = 0;
#pragma unroll
  for (int i = 1; i < 4; ++i) if (m0 >= base[i]) e = i;
  if (tid < BM) {
    int v = list[m0 + tid];
    slist[tid] = v < 0 ? 0 : v;
  }
  __syncthreads();

  int tokr[2];
#pragma unroll
  for (int i = 0; i < 2; ++i) tokr[i] = slist[i * 64 + (tid >> 2)];

  const f16* wB = w1t + (size_t)(e * FF + h0) * CDIM;
  // byte-in-row (64B rows); involution spans all 8 (parity,slot) bank groups
  int kbs = ((tid & 3) * 16) ^ (((tid >> 3) & 3) << 4);

  f32x4 acc[4][4] = {};
  int lane = tid & 63, w = tid >> 6, wr = w >> 1, wc = w & 1;

  auto stage = [&](int kk, int p) {   // 4 gloads: A 128x32, B 128x32
    char* s = smem + p * 16384;
#pragma unroll
    for (int i = 0; i < 2; ++i) {   // A: gathered x rows
      gload16(xh + (size_t)tokr[i] * CDIM + kk * BK + (kbs >> 1),
              s + i * 4096 + tid * 16);
    }
#pragma unroll
    for (int i = 0; i < 2; ++i) {   // B: w1t rows (ff cols)
      int row = i * 64 + (tid >> 2);
      gload16(wB + (size_t)row * CDIM + kk * BK + (kbs >> 1),
              s + 8192 + i * 4096 + tid * 16);
    }
  };

  auto compute = [&](int p) {
    const char* s = smem + p * 16384;
    f16x8 af[4], bfr[4];
    int kb = (lane >> 4) * 16;
#pragma unroll
    for (int fr = 0; fr < 4; ++fr) {
      int row = wr * 64 + fr * 16 + (lane & 15);
      af[fr] = *(const f16x8*)(s + row * 64 + (kb ^ (((row >> 1) & 3) << 4)));
    }
#pragma unroll
    for (int fc = 0; fc < 4; ++fc) {
      int col = wc * 64 + fc * 16 + (lane & 15);
      bfr[fc] = *(const f16x8*)(s + 8192 + col * 64 + (kb ^ (((col >> 1) & 3) << 4)));
    }
#pragma unroll
    for (int fr = 0; fr < 4; ++fr)
#pragma unroll
      for (int fc = 0; fc < 4; ++fc)
        acc[fr][fc] = __builtin_amdgcn_mfma_f32_16x16x32_f16(af[fr], bfr[fc],
                                                             acc[fr][fc], 0, 0, 0);
  };

  stage(0, 0);
  __syncthreads();
  for (int kk = 0; kk < 16; ++kk) {      // K = 512, BK = 32
    if (kk < 15) stage(kk + 1, (kk + 1) & 1);
    __builtin_amdgcn_sched_barrier(0);
    __builtin_amdgcn_s_setprio(1);
    compute(kk & 1);
    __builtin_amdgcn_s_setprio(0);
    __syncthreads();
  }

  // epilogue: gelu -> fp16, LDS repack [128][256B], coalesced 16B stores
#pragma unroll
  for (int fr = 0; fr < 4; ++fr)
#pragma unroll
    for (int fc = 0; fc < 4; ++fc)
#pragma unroll
      for (int i = 0; i < 4; ++i) {
        int row = wr * 64 + fr * 16 + (lane >> 4) * 4 + i;
        int col = wc * 64 + fc * 16 + (lane & 15);
        float v = gelu_fast(acc[fr][fc][i]);
        int off = (row * 256 + col * 2) ^ ((row & 7) << 4);
        *(f16*)(smem + off) = (f16)v;
      }
  __syncthreads();
#pragma unroll
  for (int j = 0; j < 8; ++j) {
    int row = j * 16 + (tid >> 4);
    int colb = ((tid & 15) * 16) ^ ((row & 7) << 4);
    uint4 v = *(const uint4*)(smem + row * 256 + colb);
    *(uint4*)((char*)H + ((size_t)(mloc + row) * FF + h0) * 2 + (tid & 15) * 16) = v;
  }
}

// ---------------- pass 2: Y[slot] = H[slot] @ W2e  (K = FF = 2048) ----------------
// 128x128 tile, BK=32, dbuf 2x16KB, 4 blocks/CU. Grid CB*4.

__global__ __launch_bounds__(256, 4) void k_gemm2(const f16* __restrict__ H,
                                                  const f16* __restrict__ w2t, // [E][C][FF]
                                                  const int* __restrict__ base,
                                                  f16* __restrict__ Y, int cb, int nwg) {
  __shared__ __align__(16) char smem[32768];
  int tid = threadIdx.x;
  int wk = xcd_swz(blockIdx.x, nwg);
  int bx = wk >> 2, by = wk & 3;      // 512/128 = 4 out panels, fastest
  int m0 = (cb + bx) * BM;
  int mloc = bx * BM;
  int c0 = by * BN2;
  int e = 0;
#pragma unroll
  for (int i = 1; i < 4; ++i) if (m0 >= base[i]) e = i;

  const f16* pA = H + (size_t)mloc * FF;
  const f16* wB = w2t + (size_t)(e * CDIM + c0) * FF;
  int kbs = ((tid & 3) * 16) ^ (((tid >> 3) & 3) << 4);

  f32x4 acc[4][4] = {};
  int lane = tid & 63, w = tid >> 6, wr = w >> 1, wc = w & 1;

  auto stage = [&](int kk, int p) {   // 4 gloads: A 128x32, B 128x32
    char* s = smem + p * 16384;
#pragma unroll
    for (int i = 0; i < 2; ++i) {   // A: H rows (local slots)
      int row = i * 64 + (tid >> 2);
      gload16(pA + (size_t)row * FF + kk * BK + (kbs >> 1),
              s + i * 4096 + tid * 16);
    }
#pragma unroll
    for (int i = 0; i < 2; ++i) {   // B: w2t rows (out cols)
      int row = i * 64 + (tid >> 2);
      gload16(wB + (size_t)row * FF + kk * BK + (kbs >> 1),
              s + 8192 + i * 4096 + tid * 16);
    }
  };

  auto compute = [&](int p) {
    const char* s = smem + p * 16384;
    f16x8 af[4], bfr[4];
    int kb = (lane >> 4) * 16;
#pragma unroll
    for (int fr = 0; fr < 4; ++fr) {
      int row = wr * 64 + fr * 16 + (lane & 15);
      af[fr] = *(const f16x8*)(s + row * 64 + (kb ^ (((row >> 1) & 3) << 4)));
    }
#pragma unroll
    for (int fc = 0; fc < 4; ++fc) {
      int col = wc * 64 + fc * 16 + (lane & 15);
      bfr[fc] = *(const f16x8*)(s + 8192 + col * 64 + (kb ^ (((col >> 1) & 3) << 4)));
    }
#pragma unroll
    for (int fr = 0; fr < 4; ++fr)
#pragma unroll
      for (int fc = 0; fc < 4; ++fc)
        acc[fr][fc] = __builtin_amdgcn_mfma_f32_16x16x32_f16(af[fr], bfr[fc],
                                                             acc[fr][fc], 0, 0, 0);
  };

  stage(0, 0);
  __syncthreads();
  for (int kk = 0; kk < 64; ++kk) {      // K = 2048, BK = 32
    if (kk < 63) stage(kk + 1, (kk + 1) & 1);
    __builtin_amdgcn_sched_barrier(0);
    __builtin_amdgcn_s_setprio(1);
    compute(kk & 1);
    __builtin_amdgcn_s_setprio(0);
    __syncthreads();
  }

  // epilogue: f16 -> LDS repack [128][256B] -> coalesced 16B stores
#pragma unroll
  for (int fr = 0; fr < 4; ++fr)
#pragma unroll
    for (int fc = 0; fc < 4; ++fc)
#pragma unroll
      for (int i = 0; i < 4; ++i) {
        int row = wr * 64 + fr * 16 + (lane >> 4) * 4 + i;
        int col = wc * 64 + fc * 16 + (lane & 15);
        int off = (row * 256 + col * 2) ^ ((row & 7) << 4);
        *(f16*)(smem + off) = (f16)acc[fr][fc][i];
      }
  __syncthreads();
#pragma unroll
  for (int j = 0; j < 8; ++j) {
    int row = j * 16 + (tid >> 4);
    int colb = ((tid & 15) * 16) ^ ((row & 7) << 4);
    uint4 v = *(const uint4*)(smem + row * 256 + colb);
    *(uint4*)((char*)Y + ((size_t)(m0 + row) * CDIM + c0) * 2 + (tid & 15) * 16) = v;
  }
}

// ---------------- combine: out[tok] = w0*Y[s0] + w1*Y[s1] ----------------

__global__ __launch_bounds__(256) void k_combine(const f16* __restrict__ Y,
                                                 const float4* __restrict__ tokinfo,
                                                 const int2* __restrict__ tokslot,
                                                 float* __restrict__ out) {
  int gid = blockIdx.x * 256 + threadIdx.x;
  int tok = gid >> 7;
  int cc = (gid & 127) * 4;
  int2 sl = tokslot[tok];
  float4 ti = tokinfo[tok];
  f16x4 y0 = *(const f16x4*)(Y + (size_t)sl.x * CDIM + cc);
  f16x4 y1 = *(const f16x4*)(Y + (size_t)sl.y * CDIM + cc);
  float w0 = ti.z, w1 = ti.w;
  float4 o;
  o.x = w0 * (float)y0[0] + w1 * (float)y1[0];
  o.y = w0 * (float)y0[1] + w1 * (float)y1[1];
  o.z = w0 * (float)y0[2] + w1 * (float)y1[2];
  o.w = w0 * (float)y0[3] + w1 * (float)y1[3];
  *(float4*)(out + (size_t)tok * CDIM + cc) = o;
}

// ---------------- host ----------------

extern "C" void kernel_launch(void* const* d_in, const int* in_sizes, int n_in,
                              void* d_out, int out_size, void* d_ws, size_t ws_size,
                              hipStream_t stream) {
  const float* x  = (const float*)d_in[0];
  const float* gw = (const float*)d_in[1];
  const float* w1 = (const float*)d_in[2];
  const float* w2 = (const float*)d_in[3];
  float* out  = (float*)d_out;
  float* rout = out + (size_t)NTOK * CDIM;

  char* ws = (char*)d_ws;
  f16* xh      = (f16*)ws;      ws += (size_t)NTOK * CDIM * 2;       // 16.78 MB
  f16* w1t     = (f16*)ws;      ws += (size_t)NEXP * FF * CDIM * 2;  //  8.39 MB
  f16* w2t     = (f16*)ws;      ws += (size_t)NEXP * FF * CDIM * 2;  //  8.39 MB
  f16* Ybuf    = (f16*)ws;      ws += (size_t)CAP * CDIM * 2;        // 34.08 MB
  float4* tokinfo = (float4*)ws; ws += (size_t)NTOK * 16;            //  0.26 MB
  int2* tokslot = (int2*)ws;    ws += (size_t)NTOK * 8;              //  0.13 MB
  int* list    = (int*)ws;      ws += (size_t)CAP * 4;               //  0.13 MB
  int* cnt     = (int*)ws;      ws += 4 * CPAD * 4;
  int* base    = (int*)ws;      ws += 64;
  int* cursor  = (int*)ws;      ws += 4 * CPAD * 4;
  f16* Hbuf    = (f16*)ws;      // CB*128*FF f16, sized by ladder below

  size_t base_bytes = (size_t)(ws - (char*)d_ws);
  const int opts[12] = {260, 130, 65, 52, 26, 20, 13, 10, 5, 4, 2, 1};
  int CB = 1;
  for (int oi = 0; oi < 12; ++oi) {
    if (base_bytes + (size_t)opts[oi] * BM * FF * 2 <= ws_size) { CB = opts[oi]; break; }
  }

  k_init<<<(CAP + 255) / 256, 256, 0, stream>>>(list, cnt);
  k_cast_t<<<dim3(FF / 64, CDIM / 64, NEXP), 256, 0, stream>>>(w1, w1t, CDIM, FF);
  k_cast_t<<<dim3(CDIM / 64, FF / 64, NEXP), 256, 0, stream>>>(w2, w2t, FF, CDIM);
  k_router<<<NTOK / 64, 256, 0, stream>>>(x, gw, xh, rout, tokinfo, cnt);
  k_bases<<<1, 64, 0, stream>>>(cnt, base, cursor);
  k_assign<<<NTOK / 1024, 256, 0, stream>>>(tokinfo, cursor, list, tokslot);

  for (int cb = 0; cb < NBLK; cb += CB) {
    int n1 = CB * 16, n2 = CB * 4;
    k_gemm1<<<n1, 256, 0, stream>>>(xh, w1t, list, base, Hbuf, cb, n1);
    k_gemm2<<<n2, 256, 0, stream>>>(Hbuf, w2t, base, Ybuf, cb, n2);
  }
  k_combine<<<NTOK * CDIM / 4 / 256, 256, 0, stream>>>(Ybuf, tokinfo, tokslot, out);
}